// Round 6
// baseline (378.108 us; speedup 1.0000x reference)
//
#include <hip/hip_runtime.h>
#include <cstdint>
#include <cstddef>

#define NN 50000
#define NE 800000
#define RREL 5
#define SCAN_NB 196   // ceil(NN/256)

static __device__ __forceinline__ float lrelu(float v) { return v > 0.f ? v : 0.01f * v; }

// ---------------------------------------------------------------------------
// 64x64-tile f32 GEMM (used only for e0 = x @ field_W + field_b, K=128)
// ---------------------------------------------------------------------------
template<int K>
__launch_bounds__(256)
__global__ void gemm_tile(const float* __restrict__ A, int lda,
                          const float* __restrict__ B0,
                          const float* __restrict__ bias,
                          float* __restrict__ C, int M)
{
    __shared__ float As[64][68];   // transposed: As[k][row]
    __shared__ float Bs[64][64];   // Bs[k][col]
    const int row0 = blockIdx.x * 64;
    const int t = threadIdx.x;
    const int tx = t & 15, ty = t >> 4;

    float acc[4][4] = {};

    for (int kc = 0; kc < K; kc += 64) {
        {
            int arow = t >> 4, akk = (t & 15) << 2;
            #pragma unroll
            for (int rp = 0; rp < 64; rp += 16) {
                int r = rp + arow, gr = row0 + r;
                float4 v = make_float4(0.f, 0.f, 0.f, 0.f);
                if (gr < M) v = *(const float4*)&A[(size_t)gr * lda + kc + akk];
                As[akk + 0][r] = v.x; As[akk + 1][r] = v.y;
                As[akk + 2][r] = v.z; As[akk + 3][r] = v.w;
            }
        }
        #pragma unroll
        for (int idx = t; idx < 1024; idx += 256) {
            int k = idx >> 4, c4 = (idx & 15) << 2;
            *(float4*)&Bs[k][c4] = *(const float4*)&B0[(size_t)(kc + k) * 64 + c4];
        }
        __syncthreads();

        #pragma unroll 8
        for (int k = 0; k < 64; ++k) {
            float4 av = *(const float4*)&As[k][ty * 4];
            float4 bv = *(const float4*)&Bs[k][tx * 4];
            float ar[4] = {av.x, av.y, av.z, av.w};
            float br[4] = {bv.x, bv.y, bv.z, bv.w};
            #pragma unroll
            for (int i = 0; i < 4; ++i)
                #pragma unroll
                for (int j = 0; j < 4; ++j)
                    acc[i][j] = fmaf(ar[i], br[j], acc[i][j]);
        }
        __syncthreads();
    }

    float bb[4];
    {
        const float* bp = bias + tx * 4;
        bb[0] = bp[0]; bb[1] = bp[1]; bb[2] = bp[2]; bb[3] = bp[3];
    }
    #pragma unroll
    for (int i = 0; i < 4; ++i) {
        int gr = row0 + ty * 4 + i;
        if (gr >= M) continue;
        *(float4*)&C[(size_t)gr * 64 + tx * 4] =
            make_float4(acc[i][0] + bb[0], acc[i][1] + bb[1],
                        acc[i][2] + bb[2], acc[i][3] + bb[3]);
    }
}

// ---------------------------------------------------------------------------
// zgather: one wave per dst node.
//   Z[n][r*64+lane] = sum_{e->n, type r} w_e * e_prev[src_e][lane]
//   S[n][r]         = sum_{e->n, type r} w_e        (lane 0 writes)
// ---------------------------------------------------------------------------
__launch_bounds__(256)
__global__ void zgather(const int* __restrict__ offs, const uint2* __restrict__ epack,
                        const float* __restrict__ Eprev,
                        float* __restrict__ Z, float* __restrict__ S)
{
    int wid = (blockIdx.x * 256 + threadIdx.x) >> 6;
    int lane = threadIdx.x & 63;
    if (wid >= NN) return;
    int s0 = offs[wid], s1 = offs[wid + 1];

    float a0 = 0.f, a1 = 0.f, a2 = 0.f, a3 = 0.f, a4 = 0.f;
    float s0v = 0.f, s1v = 0.f, s2v = 0.f, s3v = 0.f, s4v = 0.f;

    int p = s0;
    for (; p + 4 <= s1; p += 4) {
        uint2 q0 = epack[p + 0], q1 = epack[p + 1];
        uint2 q2 = epack[p + 2], q3 = epack[p + 3];
        float v0 = Eprev[(size_t)(q0.x & 0xFFFFu) * 64 + lane];
        float v1 = Eprev[(size_t)(q1.x & 0xFFFFu) * 64 + lane];
        float v2 = Eprev[(size_t)(q2.x & 0xFFFFu) * 64 + lane];
        float v3 = Eprev[(size_t)(q3.x & 0xFFFFu) * 64 + lane];
        #pragma unroll
        for (int ii = 0; ii < 4; ++ii) {
            uint2 q = (ii == 0) ? q0 : (ii == 1) ? q1 : (ii == 2) ? q2 : q3;
            float v = (ii == 0) ? v0 : (ii == 1) ? v1 : (ii == 2) ? v2 : v3;
            unsigned r = q.x >> 16;
            float w = __uint_as_float(q.y);
            float w0 = (r == 0) ? w : 0.f, w1 = (r == 1) ? w : 0.f;
            float w2 = (r == 2) ? w : 0.f, w3 = (r == 3) ? w : 0.f;
            float w4 = (r == 4) ? w : 0.f;
            a0 = fmaf(w0, v, a0); a1 = fmaf(w1, v, a1); a2 = fmaf(w2, v, a2);
            a3 = fmaf(w3, v, a3); a4 = fmaf(w4, v, a4);
            s0v += w0; s1v += w1; s2v += w2; s3v += w3; s4v += w4;
        }
    }
    for (; p < s1; ++p) {
        uint2 q = epack[p];
        float v = Eprev[(size_t)(q.x & 0xFFFFu) * 64 + lane];
        unsigned r = q.x >> 16;
        float w = __uint_as_float(q.y);
        float w0 = (r == 0) ? w : 0.f, w1 = (r == 1) ? w : 0.f;
        float w2 = (r == 2) ? w : 0.f, w3 = (r == 3) ? w : 0.f;
        float w4 = (r == 4) ? w : 0.f;
        a0 = fmaf(w0, v, a0); a1 = fmaf(w1, v, a1); a2 = fmaf(w2, v, a2);
        a3 = fmaf(w3, v, a3); a4 = fmaf(w4, v, a4);
        s0v += w0; s1v += w1; s2v += w2; s3v += w3; s4v += w4;
    }

    float* zr = Z + (size_t)wid * 320 + lane;
    zr[0]   = a0; zr[64]  = a1; zr[128] = a2; zr[192] = a3; zr[256] = a4;
    if (lane == 0) {
        float* sp = S + (size_t)wid * RREL;
        sp[0] = s0v; sp[1] = s1v; sp[2] = s2v; sp[3] = s3v; sp[4] = s4v;
    }
}

// ---------------------------------------------------------------------------
// zgemm v2: e_next = sum_r Z_r @ Wtop_r + sum_r S_r * (e_prev @ Wbot_r + b_r)
// 128-row x 64-col tile, acc[8][4]/thread (32 FMA per 48B LDS), 10 phases.
// A/B for phase p+1 register-prefetched during phase p's compute; barriers
// only cover LDS writes. 50KB LDS -> 3 blocks/CU -> all 391 blocks resident.
// ---------------------------------------------------------------------------
__launch_bounds__(256)
__global__ void zgemm(const float* __restrict__ Z,
                      const float* __restrict__ Eprev,
                      const float* __restrict__ relW,
                      const float* __restrict__ relb,
                      const float* __restrict__ S,
                      float* __restrict__ Enext, int M)
{
    __shared__ float As[64][132];  // As[k][row], rows 0..127 (+4 pad)
    __shared__ float Bs[64][64];   // Bs[k][col]
    const int row0 = blockIdx.x * 128;
    const int t = threadIdx.x;
    const int tx = t & 15, ty = t >> 4;

    const int arow = t >> 1;          // 0..127
    const int ak0  = (t & 1) << 5;    // 0 or 32
    const int agr  = row0 + arow;

    float4 Areg[8], Breg[4];
    // prologue: phase 0 (A = Z chunk 0, B = Wtop_0)
    {
        const float* ap = Z + (size_t)agr * 320 + ak0;
        #pragma unroll
        for (int q = 0; q < 8; ++q)
            Areg[q] = (agr < M) ? *(const float4*)(ap + (q << 2))
                                : make_float4(0.f, 0.f, 0.f, 0.f);
        #pragma unroll
        for (int j = 0; j < 4; ++j)
            Breg[j] = *(const float4*)&relW[(size_t)(t + 256 * j) * 4];
    }

    float sv[8][RREL];
    #pragma unroll
    for (int i = 0; i < 8; ++i) {
        int gr = row0 + ty * 8 + i;
        #pragma unroll
        for (int r = 0; r < RREL; ++r)
            sv[i][r] = (gr < M) ? S[(size_t)gr * RREL + r] : 0.f;
    }

    float acc[8][4] = {};

    #pragma unroll
    for (int p = 0; p < 10; ++p) {
        if (p > 0) __syncthreads();          // previous phase's readers done
        if (p <= 5) {                        // phases 6..9 reuse e_prev tile
            #pragma unroll
            for (int q = 0; q < 8; ++q) {
                int k = ak0 + (q << 2);
                As[k + 0][arow] = Areg[q].x; As[k + 1][arow] = Areg[q].y;
                As[k + 2][arow] = Areg[q].z; As[k + 3][arow] = Areg[q].w;
            }
        }
        #pragma unroll
        for (int j = 0; j < 4; ++j)
            *(float4*)&Bs[0][(size_t)(t + 256 * j) * 4] = Breg[j];
        __syncthreads();

        // prefetch phase p+1 into registers (overlaps compute below)
        if (p < 9) {
            if (p + 1 <= 5) {
                const float* ap = (p + 1 < 5)
                    ? Z + (size_t)agr * 320 + (p + 1) * 64 + ak0
                    : Eprev + (size_t)agr * 64 + ak0;
                #pragma unroll
                for (int q = 0; q < 8; ++q)
                    Areg[q] = (agr < M) ? *(const float4*)(ap + (q << 2))
                                        : make_float4(0.f, 0.f, 0.f, 0.f);
            }
            const float* bp = relW + ((p + 1 < 5) ? (size_t)(p + 1) * 8192
                                                  : (size_t)(p - 4) * 8192 + 4096);
            #pragma unroll
            for (int j = 0; j < 4; ++j)
                Breg[j] = *(const float4*)&bp[(size_t)(t + 256 * j) * 4];
        }

        if (p < 5) {
            #pragma unroll 4
            for (int k = 0; k < 64; ++k) {
                float4 a0 = *(const float4*)&As[k][ty * 8];
                float4 a1 = *(const float4*)&As[k][ty * 8 + 4];
                float4 bv = *(const float4*)&Bs[k][tx * 4];
                float ar[8] = {a0.x, a0.y, a0.z, a0.w, a1.x, a1.y, a1.z, a1.w};
                float br[4] = {bv.x, bv.y, bv.z, bv.w};
                #pragma unroll
                for (int i = 0; i < 8; ++i)
                    #pragma unroll
                    for (int j = 0; j < 4; ++j)
                        acc[i][j] = fmaf(ar[i], br[j], acc[i][j]);
            }
        } else {
            float tmp[8][4] = {};
            #pragma unroll 4
            for (int k = 0; k < 64; ++k) {
                float4 a0 = *(const float4*)&As[k][ty * 8];
                float4 a1 = *(const float4*)&As[k][ty * 8 + 4];
                float4 bv = *(const float4*)&Bs[k][tx * 4];
                float ar[8] = {a0.x, a0.y, a0.z, a0.w, a1.x, a1.y, a1.z, a1.w};
                float br[4] = {bv.x, bv.y, bv.z, bv.w};
                #pragma unroll
                for (int i = 0; i < 8; ++i)
                    #pragma unroll
                    for (int j = 0; j < 4; ++j)
                        tmp[i][j] = fmaf(ar[i], br[j], tmp[i][j]);
            }
            const int r = p - 5;
            float4 bq = *(const float4*)&relb[r * 64 + tx * 4];
            float bbr[4] = {bq.x, bq.y, bq.z, bq.w};
            #pragma unroll
            for (int i = 0; i < 8; ++i)
                #pragma unroll
                for (int j = 0; j < 4; ++j)
                    acc[i][j] = fmaf(sv[i][r], tmp[i][j] + bbr[j], acc[i][j]);
        }
    }

    #pragma unroll
    for (int i = 0; i < 8; ++i) {
        int gr = row0 + ty * 8 + i;
        if (gr >= M) continue;
        *(float4*)&Enext[(size_t)gr * 64 + tx * 4] =
            make_float4(acc[i][0], acc[i][1], acc[i][2], acc[i][3]);
    }
}

// ---------------------------------------------------------------------------
// Fused output head: out = sum_s lrelu(Es @ Ws + bs)
// ---------------------------------------------------------------------------
__launch_bounds__(256)
__global__ void head_fused(const float* __restrict__ E0, const float* __restrict__ E1,
                           const float* __restrict__ E2,
                           const float* __restrict__ W0, const float* __restrict__ W1,
                           const float* __restrict__ W2,
                           const float* __restrict__ b0, const float* __restrict__ b1,
                           const float* __restrict__ b2,
                           float* __restrict__ out, int M)
{
    __shared__ float As[64][68];
    __shared__ float Bs[64][64];
    const int row0 = blockIdx.x * 64;
    const int t = threadIdx.x;
    const int tx = t & 15, ty = t >> 4;

    const float* Es[3] = {E0, E1, E2};
    const float* Ws[3] = {W0, W1, W2};
    const float* bs[3] = {b0, b1, b2};

    float acc[4][4] = {};

    #pragma unroll
    for (int s = 0; s < 3; ++s) {
        __syncthreads();
        {
            int arow = t >> 4, akk = (t & 15) << 2;
            #pragma unroll
            for (int rp = 0; rp < 64; rp += 16) {
                int r = rp + arow, gr = row0 + r;
                float4 v = make_float4(0.f, 0.f, 0.f, 0.f);
                if (gr < M) v = *(const float4*)&Es[s][(size_t)gr * 64 + akk];
                As[akk + 0][r] = v.x; As[akk + 1][r] = v.y;
                As[akk + 2][r] = v.z; As[akk + 3][r] = v.w;
            }
        }
        #pragma unroll
        for (int idx = t; idx < 1024; idx += 256) {
            int k = idx >> 4, c4 = (idx & 15) << 2;
            *(float4*)&Bs[k][c4] = *(const float4*)&Ws[s][(size_t)k * 64 + c4];
        }
        __syncthreads();

        float tmp[4][4] = {};
        #pragma unroll 8
        for (int k = 0; k < 64; ++k) {
            float4 av = *(const float4*)&As[k][ty * 4];
            float4 bv = *(const float4*)&Bs[k][tx * 4];
            float ar[4] = {av.x, av.y, av.z, av.w};
            float br[4] = {bv.x, bv.y, bv.z, bv.w};
            #pragma unroll
            for (int i = 0; i < 4; ++i)
                #pragma unroll
                for (int j = 0; j < 4; ++j)
                    tmp[i][j] = fmaf(ar[i], br[j], tmp[i][j]);
        }
        float bb[4];
        {
            const float* bp = bs[s] + tx * 4;
            bb[0] = bp[0]; bb[1] = bp[1]; bb[2] = bp[2]; bb[3] = bp[3];
        }
        #pragma unroll
        for (int i = 0; i < 4; ++i)
            #pragma unroll
            for (int j = 0; j < 4; ++j)
                acc[i][j] += lrelu(tmp[i][j] + bb[j]);
    }

    #pragma unroll
    for (int i = 0; i < 4; ++i) {
        int gr = row0 + ty * 4 + i;
        if (gr >= M) continue;
        *(float4*)&out[(size_t)gr * 64 + tx * 4] =
            make_float4(acc[i][0], acc[i][1], acc[i][2], acc[i][3]);
    }
}

// ---------------------------------------------------------------------------
// CSR build
// ---------------------------------------------------------------------------
__launch_bounds__(256)
__global__ void deg_slot(const int* __restrict__ dst, int* __restrict__ deg,
                         int* __restrict__ slot)
{
    int e = blockIdx.x * 256 + threadIdx.x;
    if (e < NE) slot[e] = atomicAdd(&deg[dst[e]], 1);
}

__launch_bounds__(256)
__global__ void scan_block_sums(const int* __restrict__ deg, int* __restrict__ bsum)
{
    __shared__ int sh[256];
    int i = blockIdx.x * 256 + threadIdx.x;
    sh[threadIdx.x] = (i < NN) ? deg[i] : 0;
    __syncthreads();
    for (int s = 128; s > 0; s >>= 1) {
        if (threadIdx.x < s) sh[threadIdx.x] += sh[threadIdx.x + s];
        __syncthreads();
    }
    if (threadIdx.x == 0) bsum[blockIdx.x] = sh[0];
}

__launch_bounds__(256)
__global__ void scan_partials(int* __restrict__ bsum, int nb)
{
    __shared__ int sh[256];
    int t = threadIdx.x;
    int v = (t < nb) ? bsum[t] : 0;
    sh[t] = v; __syncthreads();
    for (int off = 1; off < 256; off <<= 1) {
        int x = (t >= off) ? sh[t - off] : 0;
        __syncthreads();
        sh[t] += x;
        __syncthreads();
    }
    if (t < nb) bsum[t] = sh[t] - v;   // exclusive
}

__launch_bounds__(256)
__global__ void scan_final(const int* __restrict__ deg, const int* __restrict__ bsum,
                           int* __restrict__ offs)
{
    __shared__ int sh[256];
    int t = threadIdx.x;
    int i = blockIdx.x * 256 + t;
    int v = (i < NN) ? deg[i] : 0;
    sh[t] = v; __syncthreads();
    for (int off = 1; off < 256; off <<= 1) {
        int x = (t >= off) ? sh[t - off] : 0;
        __syncthreads();
        sh[t] += x;
        __syncthreads();
    }
    int excl = sh[t] - v + bsum[blockIdx.x];
    if (i <= NN) offs[i] = excl;
}

// fused: w_e = lambda*exp(-etime.beta) computed inline; epack scatter
__launch_bounds__(256)
__global__ void scatter_pass(const int* __restrict__ src, const int* __restrict__ dst,
                             const int* __restrict__ etype,
                             const float* __restrict__ etime,
                             const float* __restrict__ beta,
                             const float* __restrict__ lambda_p,
                             const int* __restrict__ slot, const int* __restrict__ offs,
                             uint2* __restrict__ epack)
{
    int e = blockIdx.x * 256 + threadIdx.x;
    if (e >= NE) return;
    float b[12];
    #pragma unroll
    for (int j = 0; j < 12; ++j) b[j] = beta[j];
    const float* et = etime + (size_t)e * 12;
    float4 v0 = *(const float4*)(et);
    float4 v1 = *(const float4*)(et + 4);
    float4 v2 = *(const float4*)(et + 8);
    float logit = v0.x*b[0] + v0.y*b[1] + v0.z*b[2] + v0.w*b[3]
                + v1.x*b[4] + v1.y*b[5] + v1.z*b[6] + v1.w*b[7]
                + v2.x*b[8] + v2.y*b[9] + v2.z*b[10] + v2.w*b[11];
    float we = lambda_p[0] * expf(-logit);
    int p = offs[dst[e]] + slot[e];
    epack[p] = make_uint2(((unsigned)etype[e] << 16) | (unsigned)src[e],
                          __float_as_uint(we));
}

// ---------------------------------------------------------------------------
extern "C" void kernel_launch(void* const* d_in, const int* in_sizes, int n_in,
                              void* d_out, int out_size, void* d_ws, size_t ws_size,
                              hipStream_t stream)
{
    const float* x        = (const float*)d_in[0];
    const int*   eidx     = (const int*)d_in[1];
    const int*   etype    = (const int*)d_in[2];
    const float* etime    = (const float*)d_in[3];
    const float* lambda_p = (const float*)d_in[4];
    const float* beta     = (const float*)d_in[5];
    const float* field_W  = (const float*)d_in[6];
    const float* field_b  = (const float*)d_in[7];
    const float* rel1_W   = (const float*)d_in[8];
    const float* rel1_b   = (const float*)d_in[9];
    const float* rel2_W   = (const float*)d_in[10];
    const float* rel2_b   = (const float*)d_in[11];
    const float* out0_W   = (const float*)d_in[12];
    const float* out0_b   = (const float*)d_in[13];
    const float* out1_W   = (const float*)d_in[14];
    const float* out1_b   = (const float*)d_in[15];
    const float* out2_W   = (const float*)d_in[16];
    const float* out2_b   = (const float*)d_in[17];
    const int* src = eidx;
    const int* dst = eidx + NE;
    float* out = (float*)d_out;

    char* wsb = (char*)d_ws;
    size_t off = 0;
    auto carve = [&](size_t bytes) -> void* {
        void* p = (void*)(wsb + off);
        off += (bytes + 255) & ~(size_t)255;
        return p;
    };
    int*   deg    = (int*)carve((size_t)NN * 4);
    int*   offs   = (int*)carve((size_t)(NN + 1) * 4);
    int*   bsum   = (int*)carve((size_t)SCAN_NB * 4);
    int*   slot   = (int*)carve((size_t)NE * 4);            // 3.2 MB
    float* S      = (float*)carve((size_t)NN * RREL * 4);   // 1 MB
    uint2* epack  = (uint2*)carve((size_t)NE * 8);          // 6.4 MB
    float* e0     = (float*)carve((size_t)NN * 64 * 4);     // 12.8 MB
    float* e1     = (float*)carve((size_t)NN * 64 * 4);     // 12.8 MB
    float* e2     = (float*)carve((size_t)NN * 64 * 4);     // 12.8 MB
    float* Zb     = (float*)carve((size_t)NN * 320 * 4);    // 64 MB

    dim3 blk(256);
    const int NT64  = (NN + 63) / 64;      // 782
    const int NT128 = (NN + 127) / 128;    // 391
    const int EB = (NE + 255) / 256;
    const int GB = (NN * 64 + 255) / 256;  // one wave per node

    // ---- CSR build (layer-shared) ----
    hipMemsetAsync(deg, 0, (size_t)NN * 4, stream);
    deg_slot<<<EB, blk, 0, stream>>>(dst, deg, slot);
    scan_block_sums<<<SCAN_NB, blk, 0, stream>>>(deg, bsum);
    scan_partials<<<1, blk, 0, stream>>>(bsum, SCAN_NB);
    scan_final<<<SCAN_NB, blk, 0, stream>>>(deg, bsum, offs);
    scatter_pass<<<EB, blk, 0, stream>>>(src, dst, etype, etime, beta, lambda_p,
                                         slot, offs, epack);

    // ---- e0 = x @ field_W + field_b ----
    gemm_tile<128><<<dim3(NT64), blk, 0, stream>>>(x, 128, field_W, field_b, e0, NN);

    // ---- layer 1 ----
    zgather<<<GB, blk, 0, stream>>>(offs, epack, e0, Zb, S);
    zgemm<<<dim3(NT128), blk, 0, stream>>>(Zb, e0, rel1_W, rel1_b, S, e1, NN);

    // ---- layer 2 ----
    zgather<<<GB, blk, 0, stream>>>(offs, epack, e1, Zb, S);
    zgemm<<<dim3(NT128), blk, 0, stream>>>(Zb, e1, rel2_W, rel2_b, S, e2, NN);

    // ---- output head (single pass) ----
    head_fused<<<dim3(NT64), blk, 0, stream>>>(e0, e1, e2, out0_W, out1_W, out2_W,
                                               out0_b, out1_b, out2_b, out, NN);
}

// Round 7
// 321.834 us; speedup vs baseline: 1.1749x; 1.1749x over previous
//
#include <hip/hip_runtime.h>
#include <cstdint>
#include <cstddef>

#define NN 50000
#define NE 800000
#define RREL 5
#define SCAN_NB 196   // ceil(NN/256)

typedef __attribute__((ext_vector_type(8))) short short8;   // 8 bf16 (4 VGPRs)
typedef __attribute__((ext_vector_type(4))) float f32x4;

static __device__ __forceinline__ float lrelu(float v) { return v > 0.f ? v : 0.01f * v; }

static __device__ __forceinline__ unsigned short f32_bf16_rn(float x) {
    unsigned u = __float_as_uint(x);
    return (unsigned short)((u + 0x7FFFu + ((u >> 16) & 1u)) >> 16);
}

// split 8 f32 into bf16 hi + bf16 lo (x ~= hi + lo, residual ~2^-17|x|)
static __device__ __forceinline__ void split8(const float* v, short8& hi, short8& lo) {
    #pragma unroll
    for (int j = 0; j < 8; ++j) {
        unsigned short h = f32_bf16_rn(v[j]);
        float hf = __uint_as_float(((unsigned)h) << 16);
        unsigned short l = f32_bf16_rn(v[j] - hf);
        hi[j] = (short)h; lo[j] = (short)l;
    }
}

// ---------------------------------------------------------------------------
// 64x64-tile f32 GEMM (e0 = x @ field_W + field_b, K=128)
// ---------------------------------------------------------------------------
template<int K>
__launch_bounds__(256)
__global__ void gemm_tile(const float* __restrict__ A, int lda,
                          const float* __restrict__ B0,
                          const float* __restrict__ bias,
                          float* __restrict__ C, int M)
{
    __shared__ float As[64][68];
    __shared__ float Bs[64][64];
    const int row0 = blockIdx.x * 64;
    const int t = threadIdx.x;
    const int tx = t & 15, ty = t >> 4;

    float acc[4][4] = {};

    for (int kc = 0; kc < K; kc += 64) {
        {
            int arow = t >> 4, akk = (t & 15) << 2;
            #pragma unroll
            for (int rp = 0; rp < 64; rp += 16) {
                int r = rp + arow, gr = row0 + r;
                float4 v = make_float4(0.f, 0.f, 0.f, 0.f);
                if (gr < M) v = *(const float4*)&A[(size_t)gr * lda + kc + akk];
                As[akk + 0][r] = v.x; As[akk + 1][r] = v.y;
                As[akk + 2][r] = v.z; As[akk + 3][r] = v.w;
            }
        }
        #pragma unroll
        for (int idx = t; idx < 1024; idx += 256) {
            int k = idx >> 4, c4 = (idx & 15) << 2;
            *(float4*)&Bs[k][c4] = *(const float4*)&B0[(size_t)(kc + k) * 64 + c4];
        }
        __syncthreads();

        #pragma unroll 8
        for (int k = 0; k < 64; ++k) {
            float4 av = *(const float4*)&As[k][ty * 4];
            float4 bv = *(const float4*)&Bs[k][tx * 4];
            float ar[4] = {av.x, av.y, av.z, av.w};
            float br[4] = {bv.x, bv.y, bv.z, bv.w};
            #pragma unroll
            for (int i = 0; i < 4; ++i)
                #pragma unroll
                for (int j = 0; j < 4; ++j)
                    acc[i][j] = fmaf(ar[i], br[j], acc[i][j]);
        }
        __syncthreads();
    }

    float bb[4];
    {
        const float* bp = bias + tx * 4;
        bb[0] = bp[0]; bb[1] = bp[1]; bb[2] = bp[2]; bb[3] = bp[3];
    }
    #pragma unroll
    for (int i = 0; i < 4; ++i) {
        int gr = row0 + ty * 4 + i;
        if (gr >= M) continue;
        *(float4*)&C[(size_t)gr * 64 + tx * 4] =
            make_float4(acc[i][0] + bb[0], acc[i][1] + bb[1],
                        acc[i][2] + bb[2], acc[i][3] + bb[3]);
    }
}

// ---------------------------------------------------------------------------
// zgather: one wave per dst node.
//   Z[n][r*64+lane] = sum_{e->n, type r} w_e * e_prev[src_e][lane]
//   S[n][r]         = sum_{e->n, type r} w_e
// ---------------------------------------------------------------------------
__launch_bounds__(256)
__global__ void zgather(const int* __restrict__ offs, const uint2* __restrict__ epack,
                        const float* __restrict__ Eprev,
                        float* __restrict__ Z, float* __restrict__ S)
{
    int wid = (blockIdx.x * 256 + threadIdx.x) >> 6;
    int lane = threadIdx.x & 63;
    if (wid >= NN) return;
    int s0 = offs[wid], s1 = offs[wid + 1];

    float a0 = 0.f, a1 = 0.f, a2 = 0.f, a3 = 0.f, a4 = 0.f;
    float s0v = 0.f, s1v = 0.f, s2v = 0.f, s3v = 0.f, s4v = 0.f;

    int p = s0;
    for (; p + 4 <= s1; p += 4) {
        uint2 q0 = epack[p + 0], q1 = epack[p + 1];
        uint2 q2 = epack[p + 2], q3 = epack[p + 3];
        float v0 = Eprev[(size_t)(q0.x & 0xFFFFu) * 64 + lane];
        float v1 = Eprev[(size_t)(q1.x & 0xFFFFu) * 64 + lane];
        float v2 = Eprev[(size_t)(q2.x & 0xFFFFu) * 64 + lane];
        float v3 = Eprev[(size_t)(q3.x & 0xFFFFu) * 64 + lane];
        #pragma unroll
        for (int ii = 0; ii < 4; ++ii) {
            uint2 q = (ii == 0) ? q0 : (ii == 1) ? q1 : (ii == 2) ? q2 : q3;
            float v = (ii == 0) ? v0 : (ii == 1) ? v1 : (ii == 2) ? v2 : v3;
            unsigned r = q.x >> 16;
            float w = __uint_as_float(q.y);
            float w0 = (r == 0) ? w : 0.f, w1 = (r == 1) ? w : 0.f;
            float w2 = (r == 2) ? w : 0.f, w3 = (r == 3) ? w : 0.f;
            float w4 = (r == 4) ? w : 0.f;
            a0 = fmaf(w0, v, a0); a1 = fmaf(w1, v, a1); a2 = fmaf(w2, v, a2);
            a3 = fmaf(w3, v, a3); a4 = fmaf(w4, v, a4);
            s0v += w0; s1v += w1; s2v += w2; s3v += w3; s4v += w4;
        }
    }
    for (; p < s1; ++p) {
        uint2 q = epack[p];
        float v = Eprev[(size_t)(q.x & 0xFFFFu) * 64 + lane];
        unsigned r = q.x >> 16;
        float w = __uint_as_float(q.y);
        float w0 = (r == 0) ? w : 0.f, w1 = (r == 1) ? w : 0.f;
        float w2 = (r == 2) ? w : 0.f, w3 = (r == 3) ? w : 0.f;
        float w4 = (r == 4) ? w : 0.f;
        a0 = fmaf(w0, v, a0); a1 = fmaf(w1, v, a1); a2 = fmaf(w2, v, a2);
        a3 = fmaf(w3, v, a3); a4 = fmaf(w4, v, a4);
        s0v += w0; s1v += w1; s2v += w2; s3v += w3; s4v += w4;
    }

    float* zr = Z + (size_t)wid * 320 + lane;
    zr[0]   = a0; zr[64]  = a1; zr[128] = a2; zr[192] = a3; zr[256] = a4;
    if (lane == 0) {
        float* sp = S + (size_t)wid * RREL;
        sp[0] = s0v; sp[1] = s1v; sp[2] = s2v; sp[3] = s3v; sp[4] = s4v;
    }
}

// ---------------------------------------------------------------------------
// prep_wfrag: convert relW [R][128][64] f32 into MFMA fragment form, split
// bf16 hi/lo. Chunk c: c<5 -> Wtop_c, c>=5 -> Wbot_{c-5}. Within a chunk:
// region (s,nf); slot lane; frag elem j holds W[s*32+8*(lane>>4)+j][nf*16+(lane&15)].
// Layout: short8 wf[((c*2+s)*4+nf)*128 + lane*2 + {0=hi,1=lo}]
// ---------------------------------------------------------------------------
__launch_bounds__(256)
__global__ void prep_wfrag(const float* __restrict__ rel1_W, const float* __restrict__ rel2_W,
                           short8* __restrict__ wf1, short8* __restrict__ wf2)
{
    int bid = blockIdx.x;
    int layer = bid / 10, c = bid % 10;
    const float* relW = layer ? rel2_W : rel1_W;
    short8* wf = layer ? wf2 : wf1;
    int t = threadIdx.x;
    for (int sl = t; sl < 512; sl += 256) {
        int rid = sl >> 6, lane = sl & 63;
        int s = rid >> 2, nf = rid & 3;
        int g = lane >> 4, lc = lane & 15;
        int r = (c < 5) ? c : c - 5;
        const float* W = relW + (size_t)r * 8192 + ((c < 5) ? 0 : 4096);
        float v[8];
        #pragma unroll
        for (int j = 0; j < 8; ++j)
            v[j] = W[(size_t)(s * 32 + g * 8 + j) * 64 + nf * 16 + lc];
        short8 hi, lo;
        split8(v, hi, lo);
        size_t slot = (size_t)((c * 2 + s) * 4 + nf) * 64 + lane;
        wf[slot * 2]     = hi;
        wf[slot * 2 + 1] = lo;
    }
}

// ---------------------------------------------------------------------------
// zgemm_mfma: e_next = sum_c Z_c @ Wtop_c + sum_r S_r*(e_prev @ Wbot_r + b_r)
// Split-bf16 MFMA (16x16x32), 3 products per pair (AhBh + AlBh + AhBl).
// No LDS, no barriers: weights come pre-fragmented from wf (L2-hot).
// Block = 128 thr = 2 waves; wave tile 32M x 64N; grid ceil(M/64).
// ---------------------------------------------------------------------------
__launch_bounds__(128)
__global__ void zgemm_mfma(const float* __restrict__ Z,
                           const float* __restrict__ Eprev,
                           const short8* __restrict__ wf,
                           const float* __restrict__ relb,
                           const float* __restrict__ S,
                           float* __restrict__ Enext, int M)
{
    const int t = threadIdx.x;
    const int wid = t >> 6, lane = t & 63;
    const int lc = lane & 15, lg = lane >> 4;
    const int row0 = blockIdx.x * 64 + wid * 32;

    // A-side nodes (rows carried by lane&15)
    int nodeA[2]; bool okA[2];
    #pragma unroll
    for (int m = 0; m < 2; ++m) {
        int n = row0 + m * 16 + lc;
        okA[m] = (n < M);
        nodeA[m] = okA[m] ? n : 0;
    }

    // e_prev frags (bot chunks), split once
    short8 eh[2][2], el[2][2];
    #pragma unroll
    for (int m = 0; m < 2; ++m)
        #pragma unroll
        for (int s = 0; s < 2; ++s) {
            float v[8];
            const float* p = &Eprev[(size_t)nodeA[m] * 64 + s * 32 + lg * 8];
            float4 q0 = okA[m] ? *(const float4*)p       : make_float4(0,0,0,0);
            float4 q1 = okA[m] ? *(const float4*)(p + 4) : make_float4(0,0,0,0);
            v[0]=q0.x; v[1]=q0.y; v[2]=q0.z; v[3]=q0.w;
            v[4]=q1.x; v[5]=q1.y; v[6]=q1.z; v[7]=q1.w;
            split8(v, eh[m][s], el[m][s]);
        }

    f32x4 acc[2][4];
    #pragma unroll
    for (int m = 0; m < 2; ++m)
        #pragma unroll
        for (int nf = 0; nf < 4; ++nf)
            acc[m][nf] = (f32x4){0.f, 0.f, 0.f, 0.f};

    // ---- Z chunks (c = 0..4): acc += Z_c @ Wtop_c ----
    #pragma unroll
    for (int c = 0; c < 5; ++c) {
        #pragma unroll
        for (int s = 0; s < 2; ++s) {
            short8 ah[2], al[2];
            #pragma unroll
            for (int m = 0; m < 2; ++m) {
                float v[8];
                const float* p = &Z[(size_t)nodeA[m] * 320 + c * 64 + s * 32 + lg * 8];
                float4 q0 = okA[m] ? *(const float4*)p       : make_float4(0,0,0,0);
                float4 q1 = okA[m] ? *(const float4*)(p + 4) : make_float4(0,0,0,0);
                v[0]=q0.x; v[1]=q0.y; v[2]=q0.z; v[3]=q0.w;
                v[4]=q1.x; v[5]=q1.y; v[6]=q1.z; v[7]=q1.w;
                split8(v, ah[m], al[m]);
            }
            const short8* wp = wf + (size_t)(c * 2 + s) * 512 + lane * 2;
            #pragma unroll
            for (int nf = 0; nf < 4; ++nf) {
                short8 bh = wp[nf * 128];
                short8 bl = wp[nf * 128 + 1];
                #pragma unroll
                for (int m = 0; m < 2; ++m) {
                    acc[m][nf] = __builtin_amdgcn_mfma_f32_16x16x32_bf16(ah[m], bh, acc[m][nf], 0, 0, 0);
                    acc[m][nf] = __builtin_amdgcn_mfma_f32_16x16x32_bf16(al[m], bh, acc[m][nf], 0, 0, 0);
                    acc[m][nf] = __builtin_amdgcn_mfma_f32_16x16x32_bf16(ah[m], bl, acc[m][nf], 0, 0, 0);
                }
            }
        }
    }

    // S for D-rows (row carried by (lane>>4)*4 + reg)
    float sD[2][4][RREL];
    #pragma unroll
    for (int m = 0; m < 2; ++m)
        #pragma unroll
        for (int i = 0; i < 4; ++i) {
            int nd = row0 + m * 16 + lg * 4 + i;
            int ns = (nd < M) ? nd : 0;
            #pragma unroll
            for (int r = 0; r < RREL; ++r)
                sD[m][i][r] = S[(size_t)ns * RREL + r];
        }

    // ---- bot chunks (r = 0..4): acc += S_r * (e_prev @ Wbot_r) ----
    #pragma unroll
    for (int r = 0; r < RREL; ++r) {
        f32x4 tmp[2][4];
        #pragma unroll
        for (int m = 0; m < 2; ++m)
            #pragma unroll
            for (int nf = 0; nf < 4; ++nf)
                tmp[m][nf] = (f32x4){0.f, 0.f, 0.f, 0.f};
        const int c = 5 + r;
        #pragma unroll
        for (int s = 0; s < 2; ++s) {
            const short8* wp = wf + (size_t)(c * 2 + s) * 512 + lane * 2;
            #pragma unroll
            for (int nf = 0; nf < 4; ++nf) {
                short8 bh = wp[nf * 128];
                short8 bl = wp[nf * 128 + 1];
                #pragma unroll
                for (int m = 0; m < 2; ++m) {
                    tmp[m][nf] = __builtin_amdgcn_mfma_f32_16x16x32_bf16(eh[m][s], bh, tmp[m][nf], 0, 0, 0);
                    tmp[m][nf] = __builtin_amdgcn_mfma_f32_16x16x32_bf16(el[m][s], bh, tmp[m][nf], 0, 0, 0);
                    tmp[m][nf] = __builtin_amdgcn_mfma_f32_16x16x32_bf16(eh[m][s], bl, tmp[m][nf], 0, 0, 0);
                }
            }
        }
        #pragma unroll
        for (int m = 0; m < 2; ++m)
            #pragma unroll
            for (int nf = 0; nf < 4; ++nf)
                #pragma unroll
                for (int i = 0; i < 4; ++i)
                    acc[m][nf][i] += sD[m][i][r] * tmp[m][nf][i];
    }

    // ---- epilogue: bias combo + store ----
    float bbv[4][RREL];
    #pragma unroll
    for (int nf = 0; nf < 4; ++nf)
        #pragma unroll
        for (int r = 0; r < RREL; ++r)
            bbv[nf][r] = relb[r * 64 + nf * 16 + lc];

    #pragma unroll
    for (int m = 0; m < 2; ++m)
        #pragma unroll
        for (int i = 0; i < 4; ++i) {
            int nd = row0 + m * 16 + lg * 4 + i;
            if (nd >= M) continue;
            #pragma unroll
            for (int nf = 0; nf < 4; ++nf) {
                float v = acc[m][nf][i];
                #pragma unroll
                for (int r = 0; r < RREL; ++r)
                    v += sD[m][i][r] * bbv[nf][r];
                Enext[(size_t)nd * 64 + nf * 16 + lc] = v;
            }
        }
}

// ---------------------------------------------------------------------------
// Fused output head: out = sum_s lrelu(Es @ Ws + bs)
// ---------------------------------------------------------------------------
__launch_bounds__(256)
__global__ void head_fused(const float* __restrict__ E0, const float* __restrict__ E1,
                           const float* __restrict__ E2,
                           const float* __restrict__ W0, const float* __restrict__ W1,
                           const float* __restrict__ W2,
                           const float* __restrict__ b0, const float* __restrict__ b1,
                           const float* __restrict__ b2,
                           float* __restrict__ out, int M)
{
    __shared__ float As[64][68];
    __shared__ float Bs[64][64];
    const int row0 = blockIdx.x * 64;
    const int t = threadIdx.x;
    const int tx = t & 15, ty = t >> 4;

    const float* Es[3] = {E0, E1, E2};
    const float* Ws[3] = {W0, W1, W2};
    const float* bs[3] = {b0, b1, b2};

    float acc[4][4] = {};

    #pragma unroll
    for (int s = 0; s < 3; ++s) {
        __syncthreads();
        {
            int arow = t >> 4, akk = (t & 15) << 2;
            #pragma unroll
            for (int rp = 0; rp < 64; rp += 16) {
                int r = rp + arow, gr = row0 + r;
                float4 v = make_float4(0.f, 0.f, 0.f, 0.f);
                if (gr < M) v = *(const float4*)&Es[s][(size_t)gr * 64 + akk];
                As[akk + 0][r] = v.x; As[akk + 1][r] = v.y;
                As[akk + 2][r] = v.z; As[akk + 3][r] = v.w;
            }
        }
        #pragma unroll
        for (int idx = t; idx < 1024; idx += 256) {
            int k = idx >> 4, c4 = (idx & 15) << 2;
            *(float4*)&Bs[k][c4] = *(const float4*)&Ws[s][(size_t)k * 64 + c4];
        }
        __syncthreads();

        float tmp[4][4] = {};
        #pragma unroll 8
        for (int k = 0; k < 64; ++k) {
            float4 av = *(const float4*)&As[k][ty * 4];
            float4 bv = *(const float4*)&Bs[k][tx * 4];
            float ar[4] = {av.x, av.y, av.z, av.w};
            float br[4] = {bv.x, bv.y, bv.z, bv.w};
            #pragma unroll
            for (int i = 0; i < 4; ++i)
                #pragma unroll
                for (int j = 0; j < 4; ++j)
                    tmp[i][j] = fmaf(ar[i], br[j], tmp[i][j]);
        }
        float bb[4];
        {
            const float* bp = bs[s] + tx * 4;
            bb[0] = bp[0]; bb[1] = bp[1]; bb[2] = bp[2]; bb[3] = bp[3];
        }
        #pragma unroll
        for (int i = 0; i < 4; ++i)
            #pragma unroll
            for (int j = 0; j < 4; ++j)
                acc[i][j] += lrelu(tmp[i][j] + bb[j]);
    }

    #pragma unroll
    for (int i = 0; i < 4; ++i) {
        int gr = row0 + ty * 4 + i;
        if (gr >= M) continue;
        *(float4*)&out[(size_t)gr * 64 + tx * 4] =
            make_float4(acc[i][0], acc[i][1], acc[i][2], acc[i][3]);
    }
}

// ---------------------------------------------------------------------------
// CSR build
// ---------------------------------------------------------------------------
__launch_bounds__(256)
__global__ void deg_slot(const int* __restrict__ dst, int* __restrict__ deg,
                         int* __restrict__ slot)
{
    int e = blockIdx.x * 256 + threadIdx.x;
    if (e < NE) slot[e] = atomicAdd(&deg[dst[e]], 1);
}

__launch_bounds__(256)
__global__ void scan_block_sums(const int* __restrict__ deg, int* __restrict__ bsum)
{
    __shared__ int sh[256];
    int i = blockIdx.x * 256 + threadIdx.x;
    sh[threadIdx.x] = (i < NN) ? deg[i] : 0;
    __syncthreads();
    for (int s = 128; s > 0; s >>= 1) {
        if (threadIdx.x < s) sh[threadIdx.x] += sh[threadIdx.x + s];
        __syncthreads();
    }
    if (threadIdx.x == 0) bsum[blockIdx.x] = sh[0];
}

__launch_bounds__(256)
__global__ void scan_partials(int* __restrict__ bsum, int nb)
{
    __shared__ int sh[256];
    int t = threadIdx.x;
    int v = (t < nb) ? bsum[t] : 0;
    sh[t] = v; __syncthreads();
    for (int off = 1; off < 256; off <<= 1) {
        int x = (t >= off) ? sh[t - off] : 0;
        __syncthreads();
        sh[t] += x;
        __syncthreads();
    }
    if (t < nb) bsum[t] = sh[t] - v;   // exclusive
}

__launch_bounds__(256)
__global__ void scan_final(const int* __restrict__ deg, const int* __restrict__ bsum,
                           int* __restrict__ offs)
{
    __shared__ int sh[256];
    int t = threadIdx.x;
    int i = blockIdx.x * 256 + t;
    int v = (i < NN) ? deg[i] : 0;
    sh[t] = v; __syncthreads();
    for (int off = 1; off < 256; off <<= 1) {
        int x = (t >= off) ? sh[t - off] : 0;
        __syncthreads();
        sh[t] += x;
        __syncthreads();
    }
    int excl = sh[t] - v + bsum[blockIdx.x];
    if (i <= NN) offs[i] = excl;
}

// fused: w_e = lambda*exp(-etime.beta) inline; epack scatter
__launch_bounds__(256)
__global__ void scatter_pass(const int* __restrict__ src, const int* __restrict__ dst,
                             const int* __restrict__ etype,
                             const float* __restrict__ etime,
                             const float* __restrict__ beta,
                             const float* __restrict__ lambda_p,
                             const int* __restrict__ slot, const int* __restrict__ offs,
                             uint2* __restrict__ epack)
{
    int e = blockIdx.x * 256 + threadIdx.x;
    if (e >= NE) return;
    float b[12];
    #pragma unroll
    for (int j = 0; j < 12; ++j) b[j] = beta[j];
    const float* et = etime + (size_t)e * 12;
    float4 v0 = *(const float4*)(et);
    float4 v1 = *(const float4*)(et + 4);
    float4 v2 = *(const float4*)(et + 8);
    float logit = v0.x*b[0] + v0.y*b[1] + v0.z*b[2] + v0.w*b[3]
                + v1.x*b[4] + v1.y*b[5] + v1.z*b[6] + v1.w*b[7]
                + v2.x*b[8] + v2.y*b[9] + v2.z*b[10] + v2.w*b[11];
    float we = lambda_p[0] * expf(-logit);
    int p = offs[dst[e]] + slot[e];
    epack[p] = make_uint2(((unsigned)etype[e] << 16) | (unsigned)src[e],
                          __float_as_uint(we));
}

// ---------------------------------------------------------------------------
extern "C" void kernel_launch(void* const* d_in, const int* in_sizes, int n_in,
                              void* d_out, int out_size, void* d_ws, size_t ws_size,
                              hipStream_t stream)
{
    const float* x        = (const float*)d_in[0];
    const int*   eidx     = (const int*)d_in[1];
    const int*   etype    = (const int*)d_in[2];
    const float* etime    = (const float*)d_in[3];
    const float* lambda_p = (const float*)d_in[4];
    const float* beta     = (const float*)d_in[5];
    const float* field_W  = (const float*)d_in[6];
    const float* field_b  = (const float*)d_in[7];
    const float* rel1_W   = (const float*)d_in[8];
    const float* rel1_b   = (const float*)d_in[9];
    const float* rel2_W   = (const float*)d_in[10];
    const float* rel2_b   = (const float*)d_in[11];
    const float* out0_W   = (const float*)d_in[12];
    const float* out0_b   = (const float*)d_in[13];
    const float* out1_W   = (const float*)d_in[14];
    const float* out1_b   = (const float*)d_in[15];
    const float* out2_W   = (const float*)d_in[16];
    const float* out2_b   = (const float*)d_in[17];
    const int* src = eidx;
    const int* dst = eidx + NE;
    float* out = (float*)d_out;

    char* wsb = (char*)d_ws;
    size_t off = 0;
    auto carve = [&](size_t bytes) -> void* {
        void* p = (void*)(wsb + off);
        off += (bytes + 255) & ~(size_t)255;
        return p;
    };
    int*   deg    = (int*)carve((size_t)NN * 4);
    int*   offs   = (int*)carve((size_t)(NN + 1) * 4);
    int*   bsum   = (int*)carve((size_t)SCAN_NB * 4);
    int*   slot   = (int*)carve((size_t)NE * 4);            // 3.2 MB
    float* S      = (float*)carve((size_t)NN * RREL * 4);   // 1 MB
    uint2* epack  = (uint2*)carve((size_t)NE * 8);          // 6.4 MB
    float* e0     = (float*)carve((size_t)NN * 64 * 4);     // 12.8 MB
    float* e1     = (float*)carve((size_t)NN * 64 * 4);     // 12.8 MB
    float* e2     = (float*)carve((size_t)NN * 64 * 4);     // 12.8 MB
    float* Zb     = (float*)carve((size_t)NN * 320 * 4);    // 64 MB
    short8* wf1   = (short8*)carve((size_t)80 * 2048);      // 160 KB frag weights L1
    short8* wf2   = (short8*)carve((size_t)80 * 2048);      // 160 KB frag weights L2

    dim3 blk(256);
    const int NT64 = (NN + 63) / 64;       // 782
    const int EB = (NE + 255) / 256;
    const int GB = (NN * 64 + 255) / 256;  // one wave per node

    // ---- CSR build (layer-shared) + weight frag prep ----
    hipMemsetAsync(deg, 0, (size_t)NN * 4, stream);
    deg_slot<<<EB, blk, 0, stream>>>(dst, deg, slot);
    prep_wfrag<<<20, blk, 0, stream>>>(rel1_W, rel2_W, wf1, wf2);
    scan_block_sums<<<SCAN_NB, blk, 0, stream>>>(deg, bsum);
    scan_partials<<<1, blk, 0, stream>>>(bsum, SCAN_NB);
    scan_final<<<SCAN_NB, blk, 0, stream>>>(deg, bsum, offs);
    scatter_pass<<<EB, blk, 0, stream>>>(src, dst, etype, etime, beta, lambda_p,
                                         slot, offs, epack);

    // ---- e0 = x @ field_W + field_b ----
    gemm_tile<128><<<dim3(NT64), blk, 0, stream>>>(x, 128, field_W, field_b, e0, NN);

    // ---- layer 1 ----
    zgather<<<GB, blk, 0, stream>>>(offs, epack, e0, Zb, S);
    zgemm_mfma<<<dim3(NT64), dim3(128), 0, stream>>>(Zb, e0, wf1, rel1_b, S, e1, NN);

    // ---- layer 2 ----
    zgather<<<GB, blk, 0, stream>>>(offs, epack, e1, Zb, S);
    zgemm_mfma<<<dim3(NT64), dim3(128), 0, stream>>>(Zb, e1, wf2, rel2_b, S, e2, NN);

    // ---- output head (single pass) ----
    head_fused<<<dim3(NT64), blk, 0, stream>>>(e0, e1, e2, out0_W, out1_W, out2_W,
                                               out0_b, out1_b, out2_b, out, NN);
}

// Round 8
// 269.236 us; speedup vs baseline: 1.4044x; 1.1954x over previous
//
#include <hip/hip_runtime.h>
#include <cstdint>
#include <cstddef>

#define NN 50000
#define NE 800000
#define RREL 5
#define SCAN_NB 196   // ceil(NN/256)

typedef __attribute__((ext_vector_type(8))) short short8;   // 8 bf16 (4 VGPRs)
typedef __attribute__((ext_vector_type(4))) float f32x4;

static __device__ __forceinline__ float lrelu(float v) { return v > 0.f ? v : 0.01f * v; }

static __device__ __forceinline__ unsigned short f32_bf16_rn(float x) {
    unsigned u = __float_as_uint(x);
    return (unsigned short)((u + 0x7FFFu + ((u >> 16) & 1u)) >> 16);
}

// split 8 f32 (two float4) into bf16 hi + lo (x ~= hi + lo)
static __device__ __forceinline__ void split8v(float4 q0, float4 q1, short8& hi, short8& lo) {
    float v[8] = {q0.x, q0.y, q0.z, q0.w, q1.x, q1.y, q1.z, q1.w};
    #pragma unroll
    for (int j = 0; j < 8; ++j) {
        unsigned short h = f32_bf16_rn(v[j]);
        float hf = __uint_as_float(((unsigned)h) << 16);
        unsigned short l = f32_bf16_rn(v[j] - hf);
        hi[j] = (short)h; lo[j] = (short)l;
    }
}

// ---------------------------------------------------------------------------
// 64x64-tile f32 GEMM (e0 = x @ field_W + field_b, K=128)
// ---------------------------------------------------------------------------
template<int K>
__launch_bounds__(256)
__global__ void gemm_tile(const float* __restrict__ A, int lda,
                          const float* __restrict__ B0,
                          const float* __restrict__ bias,
                          float* __restrict__ C, int M)
{
    __shared__ float As[64][68];
    __shared__ float Bs[64][64];
    const int row0 = blockIdx.x * 64;
    const int t = threadIdx.x;
    const int tx = t & 15, ty = t >> 4;

    float acc[4][4] = {};

    for (int kc = 0; kc < K; kc += 64) {
        {
            int arow = t >> 4, akk = (t & 15) << 2;
            #pragma unroll
            for (int rp = 0; rp < 64; rp += 16) {
                int r = rp + arow, gr = row0 + r;
                float4 v = make_float4(0.f, 0.f, 0.f, 0.f);
                if (gr < M) v = *(const float4*)&A[(size_t)gr * lda + kc + akk];
                As[akk + 0][r] = v.x; As[akk + 1][r] = v.y;
                As[akk + 2][r] = v.z; As[akk + 3][r] = v.w;
            }
        }
        #pragma unroll
        for (int idx = t; idx < 1024; idx += 256) {
            int k = idx >> 4, c4 = (idx & 15) << 2;
            *(float4*)&Bs[k][c4] = *(const float4*)&B0[(size_t)(kc + k) * 64 + c4];
        }
        __syncthreads();

        #pragma unroll 8
        for (int k = 0; k < 64; ++k) {
            float4 av = *(const float4*)&As[k][ty * 4];
            float4 bv = *(const float4*)&Bs[k][tx * 4];
            float ar[4] = {av.x, av.y, av.z, av.w};
            float br[4] = {bv.x, bv.y, bv.z, bv.w};
            #pragma unroll
            for (int i = 0; i < 4; ++i)
                #pragma unroll
                for (int j = 0; j < 4; ++j)
                    acc[i][j] = fmaf(ar[i], br[j], acc[i][j]);
        }
        __syncthreads();
    }

    float bb[4];
    {
        const float* bp = bias + tx * 4;
        bb[0] = bp[0]; bb[1] = bp[1]; bb[2] = bp[2]; bb[3] = bp[3];
    }
    #pragma unroll
    for (int i = 0; i < 4; ++i) {
        int gr = row0 + ty * 4 + i;
        if (gr >= M) continue;
        *(float4*)&C[(size_t)gr * 64 + tx * 4] =
            make_float4(acc[i][0] + bb[0], acc[i][1] + bb[1],
                        acc[i][2] + bb[2], acc[i][3] + bb[3]);
    }
}

// ---------------------------------------------------------------------------
// zgather: one wave per dst node.
// ---------------------------------------------------------------------------
__launch_bounds__(256)
__global__ void zgather(const int* __restrict__ offs, const uint2* __restrict__ epack,
                        const float* __restrict__ Eprev,
                        float* __restrict__ Z, float* __restrict__ S)
{
    int wid = (blockIdx.x * 256 + threadIdx.x) >> 6;
    int lane = threadIdx.x & 63;
    if (wid >= NN) return;
    int s0 = offs[wid], s1 = offs[wid + 1];

    float a0 = 0.f, a1 = 0.f, a2 = 0.f, a3 = 0.f, a4 = 0.f;
    float s0v = 0.f, s1v = 0.f, s2v = 0.f, s3v = 0.f, s4v = 0.f;

    int p = s0;
    for (; p + 4 <= s1; p += 4) {
        uint2 q0 = epack[p + 0], q1 = epack[p + 1];
        uint2 q2 = epack[p + 2], q3 = epack[p + 3];
        float v0 = Eprev[(size_t)(q0.x & 0xFFFFu) * 64 + lane];
        float v1 = Eprev[(size_t)(q1.x & 0xFFFFu) * 64 + lane];
        float v2 = Eprev[(size_t)(q2.x & 0xFFFFu) * 64 + lane];
        float v3 = Eprev[(size_t)(q3.x & 0xFFFFu) * 64 + lane];
        #pragma unroll
        for (int ii = 0; ii < 4; ++ii) {
            uint2 q = (ii == 0) ? q0 : (ii == 1) ? q1 : (ii == 2) ? q2 : q3;
            float v = (ii == 0) ? v0 : (ii == 1) ? v1 : (ii == 2) ? v2 : v3;
            unsigned r = q.x >> 16;
            float w = __uint_as_float(q.y);
            float w0 = (r == 0) ? w : 0.f, w1 = (r == 1) ? w : 0.f;
            float w2 = (r == 2) ? w : 0.f, w3 = (r == 3) ? w : 0.f;
            float w4 = (r == 4) ? w : 0.f;
            a0 = fmaf(w0, v, a0); a1 = fmaf(w1, v, a1); a2 = fmaf(w2, v, a2);
            a3 = fmaf(w3, v, a3); a4 = fmaf(w4, v, a4);
            s0v += w0; s1v += w1; s2v += w2; s3v += w3; s4v += w4;
        }
    }
    for (; p < s1; ++p) {
        uint2 q = epack[p];
        float v = Eprev[(size_t)(q.x & 0xFFFFu) * 64 + lane];
        unsigned r = q.x >> 16;
        float w = __uint_as_float(q.y);
        float w0 = (r == 0) ? w : 0.f, w1 = (r == 1) ? w : 0.f;
        float w2 = (r == 2) ? w : 0.f, w3 = (r == 3) ? w : 0.f;
        float w4 = (r == 4) ? w : 0.f;
        a0 = fmaf(w0, v, a0); a1 = fmaf(w1, v, a1); a2 = fmaf(w2, v, a2);
        a3 = fmaf(w3, v, a3); a4 = fmaf(w4, v, a4);
        s0v += w0; s1v += w1; s2v += w2; s3v += w3; s4v += w4;
    }

    float* zr = Z + (size_t)wid * 320 + lane;
    zr[0]   = a0; zr[64]  = a1; zr[128] = a2; zr[192] = a3; zr[256] = a4;
    if (lane == 0) {
        float* sp = S + (size_t)wid * RREL;
        sp[0] = s0v; sp[1] = s1v; sp[2] = s2v; sp[3] = s3v; sp[4] = s4v;
    }
}

// ---------------------------------------------------------------------------
// prep_wfrag: relW [R][128][64] f32 -> split-bf16 MFMA fragments.
// Chunk c (c<5: Wtop_c, c>=5: Wbot_{c-5}) is 16 KB contiguous:
//   wf[c*1024 + (((s*4+nf)*64 + lane)*2 + h)]  (short8 units, h=0 hi / 1 lo)
// frag elem j = W[s*32 + 8*(lane>>4) + j][nf*16 + (lane&15)]
// ---------------------------------------------------------------------------
__launch_bounds__(256)
__global__ void prep_wfrag(const float* __restrict__ rel1_W, const float* __restrict__ rel2_W,
                           short8* __restrict__ wf1, short8* __restrict__ wf2)
{
    int bid = blockIdx.x;
    int layer = bid / 10, c = bid % 10;
    const float* relW = layer ? rel2_W : rel1_W;
    short8* wf = layer ? wf2 : wf1;
    int t = threadIdx.x;
    for (int sl = t; sl < 512; sl += 256) {
        int rid = sl >> 6, lane = sl & 63;
        int s = rid >> 2, nf = rid & 3;
        int g = lane >> 4, lc = lane & 15;
        int r = (c < 5) ? c : c - 5;
        const float* W = relW + (size_t)r * 8192 + ((c < 5) ? 0 : 4096);
        float4 q0, q1;
        float v[8];
        #pragma unroll
        for (int j = 0; j < 8; ++j)
            v[j] = W[(size_t)(s * 32 + g * 8 + j) * 64 + nf * 16 + lc];
        q0 = make_float4(v[0], v[1], v[2], v[3]);
        q1 = make_float4(v[4], v[5], v[6], v[7]);
        short8 hi, lo;
        split8v(q0, q1, hi, lo);
        size_t slot = (size_t)c * 1024 + (size_t)((s * 4 + nf) * 64 + lane) * 2;
        wf[slot]     = hi;
        wf[slot + 1] = lo;
    }
}

// ---------------------------------------------------------------------------
// zgemm_mfma v2: 2-phase LDS pipeline.
// Block = 512 thr = 8 waves; wave tile 16M x 64N -> 128 rows/block, grid 391.
// Per phase c (10 phases): wf chunk c (16 KB) is in LDS (double-buffered);
// chunk c+1 staged global->reg early, ds_write after barrier (T14).
// A: c<5 -> Z chunk c (register-prefetched), c>=5 -> e_prev frags (prologue).
// ---------------------------------------------------------------------------
__launch_bounds__(512)
__global__ void zgemm_mfma(const float* __restrict__ Z,
                           const float* __restrict__ Eprev,
                           const short8* __restrict__ wf,
                           const float* __restrict__ relb,
                           const float* __restrict__ S,
                           float* __restrict__ Enext, int M)
{
    __shared__ short8 wlds[2][1024];   // 2 x 16 KB

    const int t = threadIdx.x;
    const int wid = t >> 6, lane = t & 63;
    const int lc = lane & 15, lg = lane >> 4;
    const int row0 = blockIdx.x * 128 + wid * 16;

    // A-side node (rows carried by lane&15)
    const int nA = row0 + lc;
    const bool okA = (nA < M);
    const int nodeA = okA ? nA : 0;

    // staging ids: thread t handles global short8 pair (q=t>>6, lane_s=t&63, h=0/1)
    const int sq = t >> 6, sl = t & 63;
    const int wrA = (sq * 2 + 0) * 64 + sl;   // LDS slot for h=0
    const int wrB = (sq * 2 + 1) * 64 + sl;   // LDS slot for h=1

    // ---- prologue ----
    // e_prev frags (bot phases), split once
    short8 eh[2], el[2];
    #pragma unroll
    for (int s = 0; s < 2; ++s) {
        const float* p = &Eprev[(size_t)nodeA * 64 + s * 32 + lg * 8];
        float4 q0 = okA ? *(const float4*)p       : make_float4(0,0,0,0);
        float4 q1 = okA ? *(const float4*)(p + 4) : make_float4(0,0,0,0);
        split8v(q0, q1, eh[s], el[s]);
    }

    // S for D-rows (row = lg*4 + i)
    float sD[4][RREL];
    #pragma unroll
    for (int i = 0; i < 4; ++i) {
        int nd = row0 + lg * 4 + i;
        int ns = (nd < M) ? nd : 0;
        #pragma unroll
        for (int r = 0; r < RREL; ++r)
            sD[i][r] = S[(size_t)ns * RREL + r];
    }

    // stage chunk 0 into LDS buf 0
    {
        const short8* wp = wf + (size_t)t * 2;
        short8 sa = wp[0], sb = wp[1];
        wlds[0][wrA] = sa; wlds[0][wrB] = sb;
    }
    // prefetch A for phase 0 (Z chunk 0)
    float4 az0[2], az1[2];
    {
        const float* p0 = &Z[(size_t)nodeA * 320 + 0 * 64 + 0 * 32 + lg * 8];
        const float* p1 = &Z[(size_t)nodeA * 320 + 0 * 64 + 1 * 32 + lg * 8];
        az0[0] = okA ? *(const float4*)p0       : make_float4(0,0,0,0);
        az0[1] = okA ? *(const float4*)(p0 + 4) : make_float4(0,0,0,0);
        az1[0] = okA ? *(const float4*)p1       : make_float4(0,0,0,0);
        az1[1] = okA ? *(const float4*)(p1 + 4) : make_float4(0,0,0,0);
    }
    __syncthreads();

    f32x4 acc[4];
    #pragma unroll
    for (int nf = 0; nf < 4; ++nf) acc[nf] = (f32x4){0.f, 0.f, 0.f, 0.f};

    short8 sreg_a, sreg_b;       // wf stage regs
    float4 pz0[2], pz1[2];       // A prefetch regs

    #pragma unroll
    for (int c = 0; c < 10; ++c) {
        const int cb = c & 1;
        // issue next-chunk wf loads (global -> reg, no wait)
        if (c < 9) {
            const short8* wp = wf + (size_t)(c + 1) * 1024 + (size_t)t * 2;
            sreg_a = wp[0]; sreg_b = wp[1];
        }
        // issue next Z-chunk loads (phases 1..4 use them)
        if (c < 4) {
            const float* p0 = &Z[(size_t)nodeA * 320 + (c + 1) * 64 + 0 * 32 + lg * 8];
            const float* p1 = &Z[(size_t)nodeA * 320 + (c + 1) * 64 + 1 * 32 + lg * 8];
            pz0[0] = okA ? *(const float4*)p0       : make_float4(0,0,0,0);
            pz0[1] = okA ? *(const float4*)(p0 + 4) : make_float4(0,0,0,0);
            pz1[0] = okA ? *(const float4*)p1       : make_float4(0,0,0,0);
            pz1[1] = okA ? *(const float4*)(p1 + 4) : make_float4(0,0,0,0);
        }

        // A frags for this phase
        short8 Ah[2], Al[2];
        if (c < 5) {
            split8v(az0[0], az0[1], Ah[0], Al[0]);
            split8v(az1[0], az1[1], Ah[1], Al[1]);
        } else {
            Ah[0] = eh[0]; Al[0] = el[0];
            Ah[1] = eh[1]; Al[1] = el[1];
        }

        // MFMA section (reads LDS buf cb)
        if (c < 5) {
            #pragma unroll
            for (int s = 0; s < 2; ++s)
                #pragma unroll
                for (int nf = 0; nf < 4; ++nf) {
                    short8 bh = wlds[cb][((s * 4 + nf) * 2 + 0) * 64 + lane];
                    short8 bl = wlds[cb][((s * 4 + nf) * 2 + 1) * 64 + lane];
                    acc[nf] = __builtin_amdgcn_mfma_f32_16x16x32_bf16(Ah[s], bh, acc[nf], 0, 0, 0);
                    acc[nf] = __builtin_amdgcn_mfma_f32_16x16x32_bf16(Al[s], bh, acc[nf], 0, 0, 0);
                    acc[nf] = __builtin_amdgcn_mfma_f32_16x16x32_bf16(Ah[s], bl, acc[nf], 0, 0, 0);
                }
        } else {
            f32x4 tmp[4];
            #pragma unroll
            for (int nf = 0; nf < 4; ++nf) tmp[nf] = (f32x4){0.f, 0.f, 0.f, 0.f};
            #pragma unroll
            for (int s = 0; s < 2; ++s)
                #pragma unroll
                for (int nf = 0; nf < 4; ++nf) {
                    short8 bh = wlds[cb][((s * 4 + nf) * 2 + 0) * 64 + lane];
                    short8 bl = wlds[cb][((s * 4 + nf) * 2 + 1) * 64 + lane];
                    tmp[nf] = __builtin_amdgcn_mfma_f32_16x16x32_bf16(Ah[s], bh, tmp[nf], 0, 0, 0);
                    tmp[nf] = __builtin_amdgcn_mfma_f32_16x16x32_bf16(Al[s], bh, tmp[nf], 0, 0, 0);
                    tmp[nf] = __builtin_amdgcn_mfma_f32_16x16x32_bf16(Ah[s], bl, tmp[nf], 0, 0, 0);
                }
            const int r = c - 5;
            #pragma unroll
            for (int nf = 0; nf < 4; ++nf)
                #pragma unroll
                for (int i = 0; i < 4; ++i)
                    acc[nf][i] += sD[i][r] * tmp[nf][i];
        }

        // rotate A prefetch regs
        if (c < 4) {
            az0[0] = pz0[0]; az0[1] = pz0[1];
            az1[0] = pz1[0]; az1[1] = pz1[1];
        }

        // stage next chunk into the other LDS buffer
        if (c < 9) {
            __syncthreads();                 // phase c-1 readers of buf cb^1 done
            wlds[cb ^ 1][wrA] = sreg_a;
            wlds[cb ^ 1][wrB] = sreg_b;
            __syncthreads();                 // writes visible for phase c+1
        }
    }

    // ---- epilogue: bias + store ----
    float bbv[4][RREL];
    #pragma unroll
    for (int nf = 0; nf < 4; ++nf)
        #pragma unroll
        for (int r = 0; r < RREL; ++r)
            bbv[nf][r] = relb[r * 64 + nf * 16 + lc];

    #pragma unroll
    for (int i = 0; i < 4; ++i) {
        int nd = row0 + lg * 4 + i;
        if (nd >= M) continue;
        #pragma unroll
        for (int nf = 0; nf < 4; ++nf) {
            float v = acc[nf][i];
            #pragma unroll
            for (int r = 0; r < RREL; ++r)
                v += sD[i][r] * bbv[nf][r];
            Enext[(size_t)nd * 64 + nf * 16 + lc] = v;
        }
    }
}

// ---------------------------------------------------------------------------
// Fused output head: out = sum_s lrelu(Es @ Ws + bs)
// ---------------------------------------------------------------------------
__launch_bounds__(256)
__global__ void head_fused(const float* __restrict__ E0, const float* __restrict__ E1,
                           const float* __restrict__ E2,
                           const float* __restrict__ W0, const float* __restrict__ W1,
                           const float* __restrict__ W2,
                           const float* __restrict__ b0, const float* __restrict__ b1,
                           const float* __restrict__ b2,
                           float* __restrict__ out, int M)
{
    __shared__ float As[64][68];
    __shared__ float Bs[64][64];
    const int row0 = blockIdx.x * 64;
    const int t = threadIdx.x;
    const int tx = t & 15, ty = t >> 4;

    const float* Es[3] = {E0, E1, E2};
    const float* Ws[3] = {W0, W1, W2};
    const float* bs[3] = {b0, b1, b2};

    float acc[4][4] = {};

    #pragma unroll
    for (int s = 0; s < 3; ++s) {
        __syncthreads();
        {
            int arow = t >> 4, akk = (t & 15) << 2;
            #pragma unroll
            for (int rp = 0; rp < 64; rp += 16) {
                int r = rp + arow, gr = row0 + r;
                float4 v = make_float4(0.f, 0.f, 0.f, 0.f);
                if (gr < M) v = *(const float4*)&Es[s][(size_t)gr * 64 + akk];
                As[akk + 0][r] = v.x; As[akk + 1][r] = v.y;
                As[akk + 2][r] = v.z; As[akk + 3][r] = v.w;
            }
        }
        #pragma unroll
        for (int idx = t; idx < 1024; idx += 256) {
            int k = idx >> 4, c4 = (idx & 15) << 2;
            *(float4*)&Bs[k][c4] = *(const float4*)&Ws[s][(size_t)k * 64 + c4];
        }
        __syncthreads();

        float tmp[4][4] = {};
        #pragma unroll 8
        for (int k = 0; k < 64; ++k) {
            float4 av = *(const float4*)&As[k][ty * 4];
            float4 bv = *(const float4*)&Bs[k][tx * 4];
            float ar[4] = {av.x, av.y, av.z, av.w};
            float br[4] = {bv.x, bv.y, bv.z, bv.w};
            #pragma unroll
            for (int i = 0; i < 4; ++i)
                #pragma unroll
                for (int j = 0; j < 4; ++j)
                    tmp[i][j] = fmaf(ar[i], br[j], tmp[i][j]);
        }
        float bb[4];
        {
            const float* bp = bs[s] + tx * 4;
            bb[0] = bp[0]; bb[1] = bp[1]; bb[2] = bp[2]; bb[3] = bp[3];
        }
        #pragma unroll
        for (int i = 0; i < 4; ++i)
            #pragma unroll
            for (int j = 0; j < 4; ++j)
                acc[i][j] += lrelu(tmp[i][j] + bb[j]);
    }

    #pragma unroll
    for (int i = 0; i < 4; ++i) {
        int gr = row0 + ty * 4 + i;
        if (gr >= M) continue;
        *(float4*)&out[(size_t)gr * 64 + tx * 4] =
            make_float4(acc[i][0], acc[i][1], acc[i][2], acc[i][3]);
    }
}

// ---------------------------------------------------------------------------
// CSR build
// ---------------------------------------------------------------------------
__launch_bounds__(256)
__global__ void deg_slot(const int* __restrict__ dst, int* __restrict__ deg,
                         int* __restrict__ slot)
{
    int e = blockIdx.x * 256 + threadIdx.x;
    if (e < NE) slot[e] = atomicAdd(&deg[dst[e]], 1);
}

__launch_bounds__(256)
__global__ void scan_block_sums(const int* __restrict__ deg, int* __restrict__ bsum)
{
    __shared__ int sh[256];
    int i = blockIdx.x * 256 + threadIdx.x;
    sh[threadIdx.x] = (i < NN) ? deg[i] : 0;
    __syncthreads();
    for (int s = 128; s > 0; s >>= 1) {
        if (threadIdx.x < s) sh[threadIdx.x] += sh[threadIdx.x + s];
        __syncthreads();
    }
    if (threadIdx.x == 0) bsum[blockIdx.x] = sh[0];
}

__launch_bounds__(256)
__global__ void scan_partials(int* __restrict__ bsum, int nb)
{
    __shared__ int sh[256];
    int t = threadIdx.x;
    int v = (t < nb) ? bsum[t] : 0;
    sh[t] = v; __syncthreads();
    for (int off = 1; off < 256; off <<= 1) {
        int x = (t >= off) ? sh[t - off] : 0;
        __syncthreads();
        sh[t] += x;
        __syncthreads();
    }
    if (t < nb) bsum[t] = sh[t] - v;   // exclusive
}

__launch_bounds__(256)
__global__ void scan_final(const int* __restrict__ deg, const int* __restrict__ bsum,
                           int* __restrict__ offs)
{
    __shared__ int sh[256];
    int t = threadIdx.x;
    int i = blockIdx.x * 256 + t;
    int v = (i < NN) ? deg[i] : 0;
    sh[t] = v; __syncthreads();
    for (int off = 1; off < 256; off <<= 1) {
        int x = (t >= off) ? sh[t - off] : 0;
        __syncthreads();
        sh[t] += x;
        __syncthreads();
    }
    int excl = sh[t] - v + bsum[blockIdx.x];
    if (i <= NN) offs[i] = excl;
}

// fused: w_e = lambda*exp(-etime.beta) inline; epack scatter
__launch_bounds__(256)
__global__ void scatter_pass(const int* __restrict__ src, const int* __restrict__ dst,
                             const int* __restrict__ etype,
                             const float* __restrict__ etime,
                             const float* __restrict__ beta,
                             const float* __restrict__ lambda_p,
                             const int* __restrict__ slot, const int* __restrict__ offs,
                             uint2* __restrict__ epack)
{
    int e = blockIdx.x * 256 + threadIdx.x;
    if (e >= NE) return;
    float b[12];
    #pragma unroll
    for (int j = 0; j < 12; ++j) b[j] = beta[j];
    const float* et = etime + (size_t)e * 12;
    float4 v0 = *(const float4*)(et);
    float4 v1 = *(const float4*)(et + 4);
    float4 v2 = *(const float4*)(et + 8);
    float logit = v0.x*b[0] + v0.y*b[1] + v0.z*b[2] + v0.w*b[3]
                + v1.x*b[4] + v1.y*b[5] + v1.z*b[6] + v1.w*b[7]
                + v2.x*b[8] + v2.y*b[9] + v2.z*b[10] + v2.w*b[11];
    float we = lambda_p[0] * expf(-logit);
    int p = offs[dst[e]] + slot[e];
    epack[p] = make_uint2(((unsigned)etype[e] << 16) | (unsigned)src[e],
                          __float_as_uint(we));
}

// ---------------------------------------------------------------------------
extern "C" void kernel_launch(void* const* d_in, const int* in_sizes, int n_in,
                              void* d_out, int out_size, void* d_ws, size_t ws_size,
                              hipStream_t stream)
{
    const float* x        = (const float*)d_in[0];
    const int*   eidx     = (const int*)d_in[1];
    const int*   etype    = (const int*)d_in[2];
    const float* etime    = (const float*)d_in[3];
    const float* lambda_p = (const float*)d_in[4];
    const float* beta     = (const float*)d_in[5];
    const float* field_W  = (const float*)d_in[6];
    const float* field_b  = (const float*)d_in[7];
    const float* rel1_W   = (const float*)d_in[8];
    const float* rel1_b   = (const float*)d_in[9];
    const float* rel2_W   = (const float*)d_in[10];
    const float* rel2_b   = (const float*)d_in[11];
    const float* out0_W   = (const float*)d_in[12];
    const float* out0_b   = (const float*)d_in[13];
    const float* out1_W   = (const float*)d_in[14];
    const float* out1_b   = (const float*)d_in[15];
    const float* out2_W   = (const float*)d_in[16];
    const float* out2_b   = (const float*)d_in[17];
    const int* src = eidx;
    const int* dst = eidx + NE;
    float* out = (float*)d_out;

    char* wsb = (char*)d_ws;
    size_t off = 0;
    auto carve = [&](size_t bytes) -> void* {
        void* p = (void*)(wsb + off);
        off += (bytes + 255) & ~(size_t)255;
        return p;
    };
    int*   deg    = (int*)carve((size_t)NN * 4);
    int*   offs   = (int*)carve((size_t)(NN + 1) * 4);
    int*   bsum   = (int*)carve((size_t)SCAN_NB * 4);
    int*   slot   = (int*)carve((size_t)NE * 4);            // 3.2 MB
    float* S      = (float*)carve((size_t)NN * RREL * 4);   // 1 MB
    uint2* epack  = (uint2*)carve((size_t)NE * 8);          // 6.4 MB
    float* e0     = (float*)carve((size_t)NN * 64 * 4);     // 12.8 MB
    float* e1     = (float*)carve((size_t)NN * 64 * 4);     // 12.8 MB
    float* e2     = (float*)carve((size_t)NN * 64 * 4);     // 12.8 MB
    float* Zb     = (float*)carve((size_t)NN * 320 * 4);    // 64 MB
    short8* wf1   = (short8*)carve((size_t)20 * 16384);     // 320 KB frag weights L1
    short8* wf2   = (short8*)carve((size_t)20 * 16384);     // 320 KB frag weights L2

    dim3 blk(256);
    const int NT64  = (NN + 63) / 64;       // 782
    const int NT128 = (NN + 127) / 128;     // 391
    const int EB = (NE + 255) / 256;
    const int GB = (NN * 64 + 255) / 256;   // one wave per node

    // ---- CSR build (layer-shared) + weight frag prep ----
    hipMemsetAsync(deg, 0, (size_t)NN * 4, stream);
    deg_slot<<<EB, blk, 0, stream>>>(dst, deg, slot);
    prep_wfrag<<<20, blk, 0, stream>>>(rel1_W, rel2_W, wf1, wf2);
    scan_block_sums<<<SCAN_NB, blk, 0, stream>>>(deg, bsum);
    scan_partials<<<1, blk, 0, stream>>>(bsum, SCAN_NB);
    scan_final<<<SCAN_NB, blk, 0, stream>>>(deg, bsum, offs);
    scatter_pass<<<EB, blk, 0, stream>>>(src, dst, etype, etime, beta, lambda_p,
                                         slot, offs, epack);

    // ---- e0 = x @ field_W + field_b ----
    gemm_tile<128><<<dim3(NT64), blk, 0, stream>>>(x, 128, field_W, field_b, e0, NN);

    // ---- layer 1 ----
    zgather<<<GB, blk, 0, stream>>>(offs, epack, e0, Zb, S);
    zgemm_mfma<<<dim3(NT128), dim3(512), 0, stream>>>(Zb, e0, wf1, rel1_b, S, e1, NN);

    // ---- layer 2 ----
    zgather<<<GB, blk, 0, stream>>>(offs, epack, e1, Zb, S);
    zgemm_mfma<<<dim3(NT128), dim3(512), 0, stream>>>(Zb, e1, wf2, rel2_b, S, e2, NN);

    // ---- output head (single pass) ----
    head_fused<<<dim3(NT64), blk, 0, stream>>>(e0, e1, e2, out0_W, out1_W, out2_W,
                                               out0_b, out1_b, out2_b, out, NN);
}